// Round 1
// baseline (530.222 us; speedup 1.0000x reference)
//
#include <hip/hip_runtime.h>
#include <stdint.h>

typedef __bf16 bf16x8 __attribute__((ext_vector_type(8)));
typedef short s16x8 __attribute__((ext_vector_type(8)));
typedef float f32x4 __attribute__((ext_vector_type(4)));

__device__ __forceinline__ short f2bf(float f) {
  union { float f; uint32_t u; } c; c.f = f;
  uint32_t r = (c.u + 0x7fffu + ((c.u >> 16) & 1u)) >> 16;
  return (short)(uint16_t)r;
}

// ---------------- fp32 -> bf16 cast (4 elems/thread) ----------------
__global__ __launch_bounds__(256) void cast_bf16_kernel(const float* __restrict__ in,
                                                        short* __restrict__ out) {
  int i = blockIdx.x * 256 + threadIdx.x;
  float4 v = reinterpret_cast<const float4*>(in)[i];
  short4 o;
  o.x = f2bf(v.x); o.y = f2bf(v.y); o.z = f2bf(v.z); o.w = f2bf(v.w);
  reinterpret_cast<short4*>(out)[i] = o;
}

// ---------------- fp32 [R][C] -> bf16 [C][R] transpose-cast ----------------
__global__ __launch_bounds__(256) void transpose_cast_kernel(const float* __restrict__ in,
                                                             short* __restrict__ out,
                                                             int R, int C) {
  __shared__ float tile[32][33];
  int c0 = blockIdx.x * 32, r0 = blockIdx.y * 32;
  int tc = threadIdx.x & 31, tr = threadIdx.x >> 5;  // tr 0..7
#pragma unroll
  for (int p = 0; p < 4; ++p)
    tile[tr + p * 8][tc] = in[(size_t)(r0 + tr + p * 8) * C + c0 + tc];
  __syncthreads();
#pragma unroll
  for (int p = 0; p < 4; ++p)
    out[(size_t)(c0 + tr + p * 8) * R + r0 + tc] = f2bf(tile[tc][tr + p * 8]);
}

// ---------------- bf16 GEMM: C[M][ldc] = A[M][K] * Bt[N][K]^T + bias ----------------
// 128x128 tile, BK=32, 4 waves each 64x64 (4x4 frags of 16x16x32 MFMA).
template <bool OBF, bool QSCALE>
__global__ __launch_bounds__(256) void gemm128_kernel(const short* __restrict__ A,
                                                      const short* __restrict__ Bt,
                                                      const float* __restrict__ bias,
                                                      void* __restrict__ Cout,
                                                      int K, int ldc) {
  __shared__ short Asm[128 * 32];
  __shared__ short Bsm[128 * 32];
  const int tid = threadIdx.x;
  const int lane = tid & 63, wid = tid >> 6;
  const int m0 = blockIdx.y * 128, n0 = blockIdx.x * 128;
  const int wm = wid >> 1, wn = wid & 1;
  const int lr = lane & 15, lg = lane >> 4;

  f32x4 acc[4][4] = {};

  // staging slots: slot s (0..511): row = s>>2, col8 = s&3 ; 16B per slot
  const int s1 = tid, s2 = 256 + tid;
  const short* a1 = A + (size_t)(m0 + (s1 >> 2)) * K + (s1 & 3) * 8;
  const short* a2 = A + (size_t)(m0 + (s2 >> 2)) * K + (s2 & 3) * 8;
  const short* b1 = Bt + (size_t)(n0 + (s1 >> 2)) * K + (s1 & 3) * 8;
  const short* b2 = Bt + (size_t)(n0 + (s2 >> 2)) * K + (s2 & 3) * 8;

  bf16x8 av1 = *(const bf16x8*)(a1);
  bf16x8 av2 = *(const bf16x8*)(a2);
  bf16x8 bv1 = *(const bf16x8*)(b1);
  bf16x8 bv2 = *(const bf16x8*)(b2);

  for (int k0 = 0; k0 < K; k0 += 32) {
    __syncthreads();  // previous compute done reading LDS
    *(bf16x8*)&Asm[s1 * 8] = av1;
    *(bf16x8*)&Asm[s2 * 8] = av2;
    *(bf16x8*)&Bsm[s1 * 8] = bv1;
    *(bf16x8*)&Bsm[s2 * 8] = bv2;
    __syncthreads();

    // prefetch next K-step while MFMAs run
    const int kn = (k0 + 32 < K) ? (k0 + 32) : 0;
    av1 = *(const bf16x8*)(a1 + kn);
    av2 = *(const bf16x8*)(a2 + kn);
    bv1 = *(const bf16x8*)(b1 + kn);
    bv2 = *(const bf16x8*)(b2 + kn);

    bf16x8 af[4], bf[4];
#pragma unroll
    for (int mi = 0; mi < 4; ++mi)
      af[mi] = *(const bf16x8*)&Asm[(wm * 64 + mi * 16 + lr) * 32 + lg * 8];
#pragma unroll
    for (int ni = 0; ni < 4; ++ni)
      bf[ni] = *(const bf16x8*)&Bsm[(wn * 64 + ni * 16 + lr) * 32 + lg * 8];
#pragma unroll
    for (int mi = 0; mi < 4; ++mi)
#pragma unroll
      for (int ni = 0; ni < 4; ++ni)
        acc[mi][ni] = __builtin_amdgcn_mfma_f32_16x16x32_bf16(af[mi], bf[ni], acc[mi][ni], 0, 0, 0);
  }

#pragma unroll
  for (int ni = 0; ni < 4; ++ni) {
    const int col = n0 + wn * 64 + ni * 16 + lr;
    const float bv = bias[col];
    // fold softmax scale*log2e into Q columns of the QKV GEMM
    const float scale = (QSCALE && col < 1024) ? 0.18033688f : 1.0f;
#pragma unroll
    for (int mi = 0; mi < 4; ++mi) {
      const int row = m0 + wm * 64 + mi * 16 + lg * 4;
#pragma unroll
      for (int j = 0; j < 4; ++j) {
        const float v = (acc[mi][ni][j] + bv) * scale;
        if constexpr (OBF)
          ((short*)Cout)[(size_t)(row + j) * ldc + col] = f2bf(v);
        else
          ((float*)Cout)[(size_t)(row + j) * ldc + col] = v;
      }
    }
  }
}

// ---------------- V transpose: qkv V-part -> VT[b][h][64 d][2048 s] ----------------
__global__ __launch_bounds__(256) void vtrans_kernel(const short* __restrict__ qkv,
                                                     short* __restrict__ vt) {
  __shared__ short tile[64][72];
  const int tid = threadIdx.x;
  const int s0 = blockIdx.x * 64;
  const int h = blockIdx.y, b = blockIdx.z;
  const short* src = qkv + (size_t)(b * 2048 + s0) * 3072 + 2048 + h * 64;
#pragma unroll
  for (int p = 0; p < 2; ++p) {
    const int r = (tid >> 3) + p * 32;
    const int c0 = (tid & 7) * 8;
    *(s16x8*)&tile[r][c0] = *(const s16x8*)(src + (size_t)r * 3072 + c0);
  }
  __syncthreads();
  short* dst = vt + (size_t)(b * 16 + h) * 64 * 2048;
#pragma unroll
  for (int p = 0; p < 2; ++p) {
    const int d = (tid >> 3) + p * 32;
    const int sl0 = (tid & 7) * 8;
    s16x8 v;
#pragma unroll
    for (int i = 0; i < 8; ++i) v[i] = tile[sl0 + i][d];
    *(s16x8*)(dst + (size_t)d * 2048 + s0 + sl0) = v;
  }
}

// ---------------- causal flash attention ----------------
// block = 4 waves, 128 q rows (32/wave); kv tile 64. Q pre-scaled by 0.125*log2e.
__global__ __launch_bounds__(256) void attn_kernel(const short* __restrict__ qkv,
                                                   const short* __restrict__ vt,
                                                   short* __restrict__ abuf) {
  __shared__ short P_lds[4][32][72];
  const int tid = threadIdx.x;
  const int lane = tid & 63, wid = tid >> 6;
  const int lr = lane & 15, lg = lane >> 4;
  const int qt = blockIdx.x * 128;
  const int h = blockIdx.y, b = blockIdx.z;
  const int ldq = 3072;
  const short* Qb = qkv + (size_t)b * 2048 * ldq + h * 64;
  const short* Kb = Qb + 1024;
  const short* Vtb = vt + (size_t)(b * 16 + h) * 64 * 2048;
  const int qrowA = qt + wid * 32;

  bf16x8 qf[2][2];
#pragma unroll
  for (int qb = 0; qb < 2; ++qb)
#pragma unroll
    for (int g = 0; g < 2; ++g)
      qf[qb][g] = *(const bf16x8*)(Qb + (size_t)(qrowA + qb * 16 + lr) * ldq + g * 32 + lg * 8);

  f32x4 o[2][4] = {};
  float mst[2][4], lst[2][4];
#pragma unroll
  for (int qb = 0; qb < 2; ++qb)
#pragma unroll
    for (int j = 0; j < 4; ++j) { mst[qb][j] = -__builtin_inff(); lst[qb][j] = 0.f; }

  const int ntiles = ((qrowA + 31) >> 6) + 1;
  for (int t = 0; t < ntiles; ++t) {
    const int kvt = t << 6;
    bf16x8 kf[4][2];
#pragma unroll
    for (int ni = 0; ni < 4; ++ni)
#pragma unroll
      for (int g = 0; g < 2; ++g)
        kf[ni][g] = *(const bf16x8*)(Kb + (size_t)(kvt + ni * 16 + lr) * ldq + g * 32 + lg * 8);

    f32x4 s[2][4];
#pragma unroll
    for (int qb = 0; qb < 2; ++qb)
#pragma unroll
      for (int ni = 0; ni < 4; ++ni) {
        f32x4 z = {0.f, 0.f, 0.f, 0.f};
        s[qb][ni] = z;
#pragma unroll
        for (int g = 0; g < 2; ++g)
          s[qb][ni] = __builtin_amdgcn_mfma_f32_16x16x32_bf16(qf[qb][g], kf[ni][g], s[qb][ni], 0, 0, 0);
      }

    // causal mask (scores already in exp2 domain)
#pragma unroll
    for (int qb = 0; qb < 2; ++qb)
#pragma unroll
      for (int ni = 0; ni < 4; ++ni)
#pragma unroll
        for (int j = 0; j < 4; ++j) {
          const int q = qrowA + qb * 16 + lg * 4 + j;
          const int kv = kvt + ni * 16 + lr;
          if (kv > q) s[qb][ni][j] = -__builtin_inff();
        }

    float alpha[2][4];
#pragma unroll
    for (int qb = 0; qb < 2; ++qb)
#pragma unroll
      for (int j = 0; j < 4; ++j) {
        float v = fmaxf(fmaxf(s[qb][0][j], s[qb][1][j]), fmaxf(s[qb][2][j], s[qb][3][j]));
        v = fmaxf(v, __shfl_xor(v, 1, 64));
        v = fmaxf(v, __shfl_xor(v, 2, 64));
        v = fmaxf(v, __shfl_xor(v, 4, 64));
        v = fmaxf(v, __shfl_xor(v, 8, 64));
        const float mn = fmaxf(mst[qb][j], v);
        alpha[qb][j] = exp2f(mst[qb][j] - mn);
        mst[qb][j] = mn;
        lst[qb][j] *= alpha[qb][j];
      }

#pragma unroll
    for (int qb = 0; qb < 2; ++qb)
#pragma unroll
      for (int db = 0; db < 4; ++db)
#pragma unroll
        for (int j = 0; j < 4; ++j)
          o[qb][db][j] *= alpha[qb][j];

    float psum[2][4] = {};
#pragma unroll
    for (int qb = 0; qb < 2; ++qb)
#pragma unroll
      for (int ni = 0; ni < 4; ++ni)
#pragma unroll
        for (int j = 0; j < 4; ++j) {
          const float p = exp2f(s[qb][ni][j] - mst[qb][j]);
          psum[qb][j] += p;
          P_lds[wid][qb * 16 + lg * 4 + j][ni * 16 + lr] = f2bf(p);
        }
#pragma unroll
    for (int qb = 0; qb < 2; ++qb)
#pragma unroll
      for (int j = 0; j < 4; ++j) {
        float v = psum[qb][j];
        v += __shfl_xor(v, 1, 64);
        v += __shfl_xor(v, 2, 64);
        v += __shfl_xor(v, 4, 64);
        v += __shfl_xor(v, 8, 64);
        lst[qb][j] += v;
      }

    bf16x8 pa[2][2], vb[4][2];
#pragma unroll
    for (int qb = 0; qb < 2; ++qb)
#pragma unroll
      for (int g = 0; g < 2; ++g)
        pa[qb][g] = *(const bf16x8*)&P_lds[wid][qb * 16 + lr][g * 32 + lg * 8];
#pragma unroll
    for (int db = 0; db < 4; ++db)
#pragma unroll
      for (int g = 0; g < 2; ++g)
        vb[db][g] = *(const bf16x8*)(Vtb + (size_t)(db * 16 + lr) * 2048 + kvt + g * 32 + lg * 8);
#pragma unroll
    for (int qb = 0; qb < 2; ++qb)
#pragma unroll
      for (int db = 0; db < 4; ++db)
#pragma unroll
        for (int g = 0; g < 2; ++g)
          o[qb][db] = __builtin_amdgcn_mfma_f32_16x16x32_bf16(pa[qb][g], vb[db][g], o[qb][db], 0, 0, 0);
  }

#pragma unroll
  for (int qb = 0; qb < 2; ++qb) {
    float rl[4];
#pragma unroll
    for (int j = 0; j < 4; ++j) rl[j] = 1.0f / lst[qb][j];
#pragma unroll
    for (int db = 0; db < 4; ++db) {
      const int col = h * 64 + db * 16 + lr;
#pragma unroll
      for (int j = 0; j < 4; ++j) {
        const int row = b * 2048 + qrowA + qb * 16 + lg * 4 + j;
        abuf[(size_t)row * 1024 + col] = f2bf(o[qb][db][j] * rl[j]);
      }
    }
  }
}

extern "C" void kernel_launch(void* const* d_in, const int* in_sizes, int n_in,
                              void* d_out, int out_size, void* d_ws, size_t ws_size,
                              hipStream_t stream) {
  (void)in_sizes; (void)n_in; (void)out_size; (void)ws_size;
  const float* hs = (const float*)d_in[0];
  const float* w1 = (const float*)d_in[1];
  const float* b1 = (const float*)d_in[2];
  const float* w2 = (const float*)d_in[3];
  const float* b2 = (const float*)d_in[4];

  char* w = (char*)d_ws;
  short* Xb  = (short*)(w);                 // [8192][1024] bf16  16.78 MB
  short* W1T = (short*)(w + 16777216);      // [3072][1024] bf16   6.29 MB
  short* W2T = (short*)(w + 23068672);      // [1024][1024] bf16   2.10 MB
  short* QKV = (short*)(w + 25165824);      // [8192][3072] bf16  50.33 MB
  short* VT  = (short*)(w + 75497472);      // [64][64][2048] bf16 16.78 MB
  short* AB  = (short*)(w + 92274688);      // [8192][1024] bf16  16.78 MB

  cast_bf16_kernel<<<8192, 256, 0, stream>>>(hs, Xb);
  transpose_cast_kernel<<<dim3(96, 32), 256, 0, stream>>>(w1, W1T, 1024, 3072);
  transpose_cast_kernel<<<dim3(32, 32), 256, 0, stream>>>(w2, W2T, 1024, 1024);
  gemm128_kernel<true, true><<<dim3(24, 64), 256, 0, stream>>>(Xb, W1T, b1, QKV, 1024, 3072);
  vtrans_kernel<<<dim3(32, 16, 4), 256, 0, stream>>>(QKV, VT);
  attn_kernel<<<dim3(16, 16, 4), 256, 0, stream>>>(QKV, VT, AB);
  gemm128_kernel<false, false><<<dim3(8, 64), 256, 0, stream>>>(AB, W2T, b2, d_out, 1024, 1024);
}

// Round 2
// 388.924 us; speedup vs baseline: 1.3633x; 1.3633x over previous
//
#include <hip/hip_runtime.h>
#include <stdint.h>

typedef __bf16 bf16x8 __attribute__((ext_vector_type(8)));
typedef short s16x8 __attribute__((ext_vector_type(8)));
typedef float f32x4 __attribute__((ext_vector_type(4)));

__device__ __forceinline__ short f2bf(float f) {
  union { float f; uint32_t u; } c; c.f = f;
  uint32_t r = (c.u + 0x7fffu + ((c.u >> 16) & 1u)) >> 16;
  return (short)(uint16_t)r;
}

// async global -> LDS direct copy, 16B per lane (guide §5 common-mistake #1)
__device__ __forceinline__ void async_copy16(short* lds, const short* g) {
  __builtin_amdgcn_global_load_lds((const __attribute__((address_space(1))) void*)g,
                                   (__attribute__((address_space(3))) void*)lds,
                                   16, 0, 0);
}

// ---------------- fp32 -> bf16 cast (4 elems/thread) ----------------
__global__ __launch_bounds__(256) void cast_bf16_kernel(const float* __restrict__ in,
                                                        short* __restrict__ out) {
  int i = blockIdx.x * 256 + threadIdx.x;
  float4 v = reinterpret_cast<const float4*>(in)[i];
  short4 o;
  o.x = f2bf(v.x); o.y = f2bf(v.y); o.z = f2bf(v.z); o.w = f2bf(v.w);
  reinterpret_cast<short4*>(out)[i] = o;
}

// ---------------- fp32 [R][C] -> bf16 [C][R] transpose-cast ----------------
__global__ __launch_bounds__(256) void transpose_cast_kernel(const float* __restrict__ in,
                                                             short* __restrict__ out,
                                                             int R, int C) {
  __shared__ float tile[32][33];
  int c0 = blockIdx.x * 32, r0 = blockIdx.y * 32;
  int tc = threadIdx.x & 31, tr = threadIdx.x >> 5;  // tr 0..7
#pragma unroll
  for (int p = 0; p < 4; ++p)
    tile[tr + p * 8][tc] = in[(size_t)(r0 + tr + p * 8) * C + c0 + tc];
  __syncthreads();
#pragma unroll
  for (int p = 0; p < 4; ++p)
    out[(size_t)(c0 + tr + p * 8) * R + r0 + tc] = f2bf(tile[tc][tr + p * 8]);
}

// ---------------- bf16 GEMM: C[M][ldc] = A[M][K] * Bt[N][K]^T + bias ----------------
// 128x128 tile, BK=32, 4 waves each 64x64 (4x4 frags of 16x16x32 MFMA).
// Staging via global_load_lds width=16 (m97 structure).
template <bool OBF, bool QSCALE>
__global__ __launch_bounds__(256) void gemm128_kernel(const short* __restrict__ A,
                                                      const short* __restrict__ Bt,
                                                      const float* __restrict__ bias,
                                                      void* __restrict__ Cout,
                                                      int K, int ldc) {
  __shared__ short Asm[128 * 32];
  __shared__ short Bsm[128 * 32];
  const int tid = threadIdx.x;
  const int lane = tid & 63, wid = tid >> 6;
  const int m0 = blockIdx.y * 128, n0 = blockIdx.x * 128;
  const int wm = wid >> 1, wn = wid & 1;
  const int lr = lane & 15, lg = lane >> 4;

  f32x4 acc[4][4] = {};

  // staging slots: slot s (0..511): row = s>>2, col8 = s&3 ; 16B per slot
  // LDS dest is wave-uniform base + lane*16 (global_load_lds constraint).
  const int s1 = tid, s2 = 256 + tid;
  const short* a1 = A + (size_t)(m0 + (s1 >> 2)) * K + (s1 & 3) * 8;
  const short* a2 = A + (size_t)(m0 + (s2 >> 2)) * K + (s2 & 3) * 8;
  const short* b1 = Bt + (size_t)(n0 + (s1 >> 2)) * K + (s1 & 3) * 8;
  const short* b2 = Bt + (size_t)(n0 + (s2 >> 2)) * K + (s2 & 3) * 8;

  for (int k0 = 0; k0 < K; k0 += 32) {
    __syncthreads();  // previous compute done reading LDS
    async_copy16(&Asm[s1 * 8], a1 + k0);
    async_copy16(&Asm[s2 * 8], a2 + k0);
    async_copy16(&Bsm[s1 * 8], b1 + k0);
    async_copy16(&Bsm[s2 * 8], b2 + k0);
    __syncthreads();  // compiler drains vmcnt before barrier

    bf16x8 af[4], bf[4];
#pragma unroll
    for (int mi = 0; mi < 4; ++mi)
      af[mi] = *(const bf16x8*)&Asm[(wm * 64 + mi * 16 + lr) * 32 + lg * 8];
#pragma unroll
    for (int ni = 0; ni < 4; ++ni)
      bf[ni] = *(const bf16x8*)&Bsm[(wn * 64 + ni * 16 + lr) * 32 + lg * 8];
    __builtin_amdgcn_s_setprio(1);
#pragma unroll
    for (int mi = 0; mi < 4; ++mi)
#pragma unroll
      for (int ni = 0; ni < 4; ++ni)
        acc[mi][ni] = __builtin_amdgcn_mfma_f32_16x16x32_bf16(af[mi], bf[ni], acc[mi][ni], 0, 0, 0);
    __builtin_amdgcn_s_setprio(0);
  }

#pragma unroll
  for (int ni = 0; ni < 4; ++ni) {
    const int col = n0 + wn * 64 + ni * 16 + lr;
    const float bv = bias[col];
    // fold softmax scale*log2e into Q columns of the QKV GEMM
    const float scale = (QSCALE && col < 1024) ? 0.18033688f : 1.0f;
#pragma unroll
    for (int mi = 0; mi < 4; ++mi) {
      const int row = m0 + wm * 64 + mi * 16 + lg * 4;
#pragma unroll
      for (int j = 0; j < 4; ++j) {
        const float v = (acc[mi][ni][j] + bv) * scale;
        if constexpr (OBF)
          ((short*)Cout)[(size_t)(row + j) * ldc + col] = f2bf(v);
        else
          ((float*)Cout)[(size_t)(row + j) * ldc + col] = v;
      }
    }
  }
}

// ---------------- V transpose: qkv V-part -> VT[b][h][64 d][2048 s] ----------------
__global__ __launch_bounds__(256) void vtrans_kernel(const short* __restrict__ qkv,
                                                     short* __restrict__ vt) {
  __shared__ short tile[64][72];
  const int tid = threadIdx.x;
  const int s0 = blockIdx.x * 64;
  const int h = blockIdx.y, b = blockIdx.z;
  const short* src = qkv + (size_t)(b * 2048 + s0) * 3072 + 2048 + h * 64;
#pragma unroll
  for (int p = 0; p < 2; ++p) {
    const int r = (tid >> 3) + p * 32;
    const int c0 = (tid & 7) * 8;
    *(s16x8*)&tile[r][c0] = *(const s16x8*)(src + (size_t)r * 3072 + c0);
  }
  __syncthreads();
  short* dst = vt + (size_t)(b * 16 + h) * 64 * 2048;
#pragma unroll
  for (int p = 0; p < 2; ++p) {
    const int d = (tid >> 3) + p * 32;
    const int sl0 = (tid & 7) * 8;
    s16x8 v;
#pragma unroll
    for (int i = 0; i < 8; ++i) v[i] = tile[sl0 + i][d];
    *(s16x8*)(dst + (size_t)d * 2048 + s0 + sl0) = v;
  }
}

// ---------------- causal flash attention ----------------
// grid (8,16,4): block x processes q-tile pair {15-x, x} -> uniform work (17 kv-tiles).
// 4 waves, 32 q-rows/wave; kv tile 64. Q pre-scaled by 0.125*log2e.
__global__ __launch_bounds__(256) void attn_kernel(const short* __restrict__ qkv,
                                                   const short* __restrict__ vt,
                                                   short* __restrict__ abuf) {
  __shared__ short P_lds[4][32][72];
  const int tid = threadIdx.x;
  const int lane = tid & 63, wid = tid >> 6;
  const int lr = lane & 15, lg = lane >> 4;
  const int h = blockIdx.y, b = blockIdx.z;
  const int ldq = 3072;
  const short* Qb = qkv + (size_t)b * 2048 * ldq + h * 64;
  const short* Kb = Qb + 1024;
  const short* Vtb = vt + (size_t)(b * 16 + h) * 64 * 2048;

  for (int pp = 0; pp < 2; ++pp) {
    const int qtile = pp ? (int)blockIdx.x : 15 - (int)blockIdx.x;
    const int qrowA = qtile * 128 + wid * 32;

    bf16x8 qf[2][2];
#pragma unroll
    for (int qb = 0; qb < 2; ++qb)
#pragma unroll
      for (int g = 0; g < 2; ++g)
        qf[qb][g] = *(const bf16x8*)(Qb + (size_t)(qrowA + qb * 16 + lr) * ldq + g * 32 + lg * 8);

    f32x4 o[2][4] = {};
    float mst[2][4], lst[2][4];
#pragma unroll
    for (int qb = 0; qb < 2; ++qb)
#pragma unroll
      for (int j = 0; j < 4; ++j) { mst[qb][j] = -__builtin_inff(); lst[qb][j] = 0.f; }

    const int ntiles = ((qrowA + 31) >> 6) + 1;

    // prefetch K tile 0
    bf16x8 kf[4][2];
#pragma unroll
    for (int ni = 0; ni < 4; ++ni)
#pragma unroll
      for (int g = 0; g < 2; ++g)
        kf[ni][g] = *(const bf16x8*)(Kb + (size_t)(ni * 16 + lr) * ldq + g * 32 + lg * 8);

    for (int t = 0; t < ntiles; ++t) {
      const int kvt = t << 6;

      f32x4 s[2][4];
      __builtin_amdgcn_s_setprio(1);
#pragma unroll
      for (int qb = 0; qb < 2; ++qb)
#pragma unroll
        for (int ni = 0; ni < 4; ++ni) {
          f32x4 z = {0.f, 0.f, 0.f, 0.f};
          s[qb][ni] = z;
#pragma unroll
          for (int g = 0; g < 2; ++g)
            s[qb][ni] = __builtin_amdgcn_mfma_f32_16x16x32_bf16(qf[qb][g], kf[ni][g], s[qb][ni], 0, 0, 0);
        }
      __builtin_amdgcn_s_setprio(0);

      // prefetch next K tile (hidden under softmax + PV)
      bf16x8 kn[4][2];
      if (t + 1 < ntiles) {
        const int kvn = kvt + 64;
#pragma unroll
        for (int ni = 0; ni < 4; ++ni)
#pragma unroll
          for (int g = 0; g < 2; ++g)
            kn[ni][g] = *(const bf16x8*)(Kb + (size_t)(kvn + ni * 16 + lr) * ldq + g * 32 + lg * 8);
      }
      // V for current tile: issue before softmax VALU so latency hides
      bf16x8 vb[4][2];
#pragma unroll
      for (int db = 0; db < 4; ++db)
#pragma unroll
        for (int g = 0; g < 2; ++g)
          vb[db][g] = *(const bf16x8*)(Vtb + (size_t)(db * 16 + lr) * 2048 + kvt + g * 32 + lg * 8);

      // causal mask only on diagonal-overlap tiles (wave-uniform branch)
      if (kvt + 63 > qrowA) {
#pragma unroll
        for (int qb = 0; qb < 2; ++qb)
#pragma unroll
          for (int ni = 0; ni < 4; ++ni)
#pragma unroll
            for (int j = 0; j < 4; ++j) {
              const int q = qrowA + qb * 16 + lg * 4 + j;
              const int kv = kvt + ni * 16 + lr;
              if (kv > q) s[qb][ni][j] = -__builtin_inff();
            }
      }

      float alpha[2][4];
#pragma unroll
      for (int qb = 0; qb < 2; ++qb)
#pragma unroll
        for (int j = 0; j < 4; ++j) {
          float v = fmaxf(fmaxf(s[qb][0][j], s[qb][1][j]), fmaxf(s[qb][2][j], s[qb][3][j]));
          v = fmaxf(v, __shfl_xor(v, 1, 64));
          v = fmaxf(v, __shfl_xor(v, 2, 64));
          v = fmaxf(v, __shfl_xor(v, 4, 64));
          v = fmaxf(v, __shfl_xor(v, 8, 64));
          const float mn = fmaxf(mst[qb][j], v);
          alpha[qb][j] = exp2f(mst[qb][j] - mn);
          mst[qb][j] = mn;
          lst[qb][j] *= alpha[qb][j];
        }

#pragma unroll
      for (int qb = 0; qb < 2; ++qb)
#pragma unroll
        for (int db = 0; db < 4; ++db)
#pragma unroll
          for (int j = 0; j < 4; ++j)
            o[qb][db][j] *= alpha[qb][j];

      float psum[2][4] = {};
#pragma unroll
      for (int qb = 0; qb < 2; ++qb)
#pragma unroll
        for (int ni = 0; ni < 4; ++ni)
#pragma unroll
          for (int j = 0; j < 4; ++j) {
            const float p = exp2f(s[qb][ni][j] - mst[qb][j]);
            psum[qb][j] += p;
            P_lds[wid][qb * 16 + lg * 4 + j][ni * 16 + lr] = f2bf(p);
          }
#pragma unroll
      for (int qb = 0; qb < 2; ++qb)
#pragma unroll
        for (int j = 0; j < 4; ++j) {
          float v = psum[qb][j];
          v += __shfl_xor(v, 1, 64);
          v += __shfl_xor(v, 2, 64);
          v += __shfl_xor(v, 4, 64);
          v += __shfl_xor(v, 8, 64);
          lst[qb][j] += v;
        }

      bf16x8 pa[2][2];
#pragma unroll
      for (int qb = 0; qb < 2; ++qb)
#pragma unroll
        for (int g = 0; g < 2; ++g)
          pa[qb][g] = *(const bf16x8*)&P_lds[wid][qb * 16 + lr][g * 32 + lg * 8];

      __builtin_amdgcn_s_setprio(1);
#pragma unroll
      for (int qb = 0; qb < 2; ++qb)
#pragma unroll
        for (int db = 0; db < 4; ++db)
#pragma unroll
          for (int g = 0; g < 2; ++g)
            o[qb][db] = __builtin_amdgcn_mfma_f32_16x16x32_bf16(pa[qb][g], vb[db][g], o[qb][db], 0, 0, 0);
      __builtin_amdgcn_s_setprio(0);

#pragma unroll
      for (int ni = 0; ni < 4; ++ni)
#pragma unroll
        for (int g = 0; g < 2; ++g)
          kf[ni][g] = kn[ni][g];
    }

#pragma unroll
    for (int qb = 0; qb < 2; ++qb) {
      float rl[4];
#pragma unroll
      for (int j = 0; j < 4; ++j) rl[j] = 1.0f / lst[qb][j];
#pragma unroll
      for (int db = 0; db < 4; ++db) {
        const int col = h * 64 + db * 16 + lr;
#pragma unroll
        for (int j = 0; j < 4; ++j) {
          const int row = b * 2048 + qrowA + qb * 16 + lg * 4 + j;
          abuf[(size_t)row * 1024 + col] = f2bf(o[qb][db][j] * rl[j]);
        }
      }
    }
  }
}

extern "C" void kernel_launch(void* const* d_in, const int* in_sizes, int n_in,
                              void* d_out, int out_size, void* d_ws, size_t ws_size,
                              hipStream_t stream) {
  (void)in_sizes; (void)n_in; (void)out_size; (void)ws_size;
  const float* hs = (const float*)d_in[0];
  const float* w1 = (const float*)d_in[1];
  const float* b1 = (const float*)d_in[2];
  const float* w2 = (const float*)d_in[3];
  const float* b2 = (const float*)d_in[4];

  char* w = (char*)d_ws;
  short* Xb  = (short*)(w);                 // [8192][1024] bf16  16.78 MB
  short* W1T = (short*)(w + 16777216);      // [3072][1024] bf16   6.29 MB
  short* W2T = (short*)(w + 23068672);      // [1024][1024] bf16   2.10 MB
  short* QKV = (short*)(w + 25165824);      // [8192][3072] bf16  50.33 MB
  short* VT  = (short*)(w + 75497472);      // [64][64][2048] bf16 16.78 MB
  short* AB  = (short*)(w + 92274688);      // [8192][1024] bf16  16.78 MB

  cast_bf16_kernel<<<8192, 256, 0, stream>>>(hs, Xb);
  transpose_cast_kernel<<<dim3(96, 32), 256, 0, stream>>>(w1, W1T, 1024, 3072);
  transpose_cast_kernel<<<dim3(32, 32), 256, 0, stream>>>(w2, W2T, 1024, 1024);
  gemm128_kernel<true, true><<<dim3(24, 64), 256, 0, stream>>>(Xb, W1T, b1, QKV, 1024, 3072);
  vtrans_kernel<<<dim3(32, 16, 4), 256, 0, stream>>>(QKV, VT);
  attn_kernel<<<dim3(8, 16, 4), 256, 0, stream>>>(QKV, VT, AB);
  gemm128_kernel<false, false><<<dim3(8, 64), 256, 0, stream>>>(AB, W2T, b2, d_out, 1024, 1024);
}